// Round 5
// baseline (264.862 us; speedup 1.0000x reference)
//
#include <hip/hip_runtime.h>
#include <math.h>

// Problem constants (from reference)
#define BB 64
#define TT 8192
#define NH 8
#define HD 10
#define DD 80            // NH*HD floats per (b,t) row
#define NCHUNK 32        // K1: T-chunks per b (TT/256)
// ks scale: (1/sqrt(10)) * 2*log2(e)  -> makes ex = exp2(-|q*ks2|) == e^{-2s}
#define KSCALE 0.9123740929154171f
#define LOG2E  1.4426950408889634f

// ---------------------------------------------------------------------------
// K1: per-(b,chunk) partial column sums of x, race-free.
// gpart[(b*32+chunk)*80 + d] = sum over the chunk's 256 rows of x[b][t][d].
// 2048 blocks x 320 threads; each wave's loads are 1KB contiguous (addr = tid+320k).
// ---------------------------------------------------------------------------
__global__ __launch_bounds__(320) void ksum_kernel(const float* __restrict__ x,
                                                   float* __restrict__ gpart) {
    int chunk = blockIdx.x & (NCHUNK - 1);
    int b     = blockIdx.x >> 5;
    const float4* xp = (const float4*)(x + ((size_t)b * TT + (size_t)chunk * 256) * DD);

    int tid = threadIdx.x;
    int c4  = tid % 20;
    int r0  = tid / 20;

    float4 acc = make_float4(0.f, 0.f, 0.f, 0.f);
#pragma unroll
    for (int k = 0; k < 16; ++k) {
        float4 v = xp[(size_t)(r0 + k * 16) * 20 + c4];
        acc.x += v.x; acc.y += v.y; acc.z += v.z; acc.w += v.w;
    }

    __shared__ float red[320][4];
    red[tid][0] = acc.x; red[tid][1] = acc.y; red[tid][2] = acc.z; red[tid][3] = acc.w;
    __syncthreads();

    if (tid < DD) {
        int cc4 = tid >> 2, comp = tid & 3;
        float s = 0.f;
#pragma unroll
        for (int rr = 0; rr < 16; ++rr) s += red[cc4 + 20 * rr][comp];
        gpart[(b * NCHUNK + chunk) * DD + tid] = s;
    }
}

// ---------------------------------------------------------------------------
// K1.5: finalize ks[b][d] = (sum_c gpart) * KSCALE. 64 blocks.
// ---------------------------------------------------------------------------
__global__ __launch_bounds__(128) void ksfin_kernel(const float* __restrict__ gpart,
                                                    float* __restrict__ ksf) {
    int b = blockIdx.x;
    int d = threadIdx.x;
    if (d < DD) {
        float s = 0.f;
#pragma unroll
        for (int c = 0; c < NCHUNK; ++c) s += gpart[(b * NCHUNK + c) * DD + d];
        ksf[b * DD + d] = s * KSCALE;
    }
}

// ---------------------------------------------------------------------------
// K2 (restructured): NO x-staging, NO barrier on the x path.
// One thread owns one (row, head-group of 4): reads its 40 floats directly as
// 10 independent global_load_dwordx4 (L3-warm after K1), computes heads
// 4g..4g+3, writes 4 coalesced 256B segments.
// Block 256 = 4 waves: half = tid>>7 selects row sub-block, g = (tid>>6)&1
// selects head group (wave-uniform). Grid 4096 blocks = 128 rows/block.
// Only ks (80 floats) goes through LDS (one tiny barrier, broadcast reads).
// ---------------------------------------------------------------------------
__global__ __launch_bounds__(256, 4) void attn_kernel(const float* __restrict__ x,
                                                      const float* __restrict__ ksf,
                                                      float* __restrict__ out) {
    int tid  = threadIdx.x;
    int r    = tid & 63;
    int g    = (tid >> 6) & 1;             // head group: heads 4g..4g+3
    int half = tid >> 7;                   // row sub-block 0/1
    int row  = blockIdx.x * 128 + half * 64 + r;   // global (b,t) row
    int b    = row >> 13;
    int t    = row & (TT - 1);

    __shared__ float ks[DD];
    if (tid < 20) *(float4*)&ks[tid * 4] = ((const float4*)ksf)[b * 20 + tid];
    __syncthreads();

    // 10 independent 16B loads: floats [g*40, g*40+40) of this row
    const float4* xp = (const float4*)x + (size_t)row * 20 + g * 10;
    float q[40];
#pragma unroll
    for (int k = 0; k < 10; ++k) {
        float4 v = xp[k];
        q[4 * k] = v.x; q[4 * k + 1] = v.y; q[4 * k + 2] = v.z; q[4 * k + 3] = v.w;
    }

#pragma unroll
    for (int hh = 0; hh < 4; ++hh) {
        int h = g * 4 + hh;
        float esum = 0.f, eq = 0.f;
#pragma unroll
        for (int d = 0; d < 10; ++d) {
            float qv  = q[hh * 10 + d];
            float sv  = qv * ks[h * HD + d];                    // broadcast LDS read
            float ex  = __builtin_amdgcn_exp2f(-fabsf(sv));     // e^{-2|s|}
            float num = __builtin_fmaf(-LOG2E, ex, LOG2E);      // log2e*(1-ex)
            float tm  = num * __builtin_amdgcn_rcpf(1.f + ex);  // log2e*|tanh|
            float e   = __builtin_amdgcn_exp2f(copysignf(tm, sv));
            esum += e;
            eq    = __builtin_fmaf(e, qv, eq);
        }
        out[((size_t)(b * NH + h)) * TT + t] = eq * __builtin_amdgcn_rcpf(esum);
    }
}

extern "C" void kernel_launch(void* const* d_in, const int* in_sizes, int n_in,
                              void* d_out, int out_size, void* d_ws, size_t ws_size,
                              hipStream_t stream) {
    const float* x = (const float*)d_in[0];
    // d_in[1] (w_proj) / d_in[2] (b_proj): dead (softmax over size-1 axis == 1)
    float* out   = (float*)d_out;
    float* gpart = (float*)d_ws;                        // 64*32*80 floats
    float* ksf   = gpart + BB * NCHUNK * DD;            // 64*80 floats

    ksum_kernel <<<dim3(BB * NCHUNK),        dim3(320), 0, stream>>>(x, gpart);
    ksfin_kernel<<<dim3(BB),                 dim3(128), 0, stream>>>(gpart, ksf);
    attn_kernel <<<dim3(BB * TT / 128),      dim3(256), 0, stream>>>(x, ksf, out);
}